// Round 10
// baseline (21.885 us; speedup 1.0000x reference)
//
#include <hip/hip_runtime.h>
#include <hip/hip_bf16.h>

// Problem constants (SparseEmbeddingHead): B=32, S=512, H=1024, V=250002
#define BB 32
#define SS 512
#define HH 1024
#define VV 250002
#define TOKENS (BB * SS)          // 16384
#define OUT_FLOATS (BB * VV)      // 8000064 (divisible by 4)
#define OUT_F4 (OUT_FLOATS / 4)   // 2000016

#define K1_BLOCKS 512
#define K1_THREADS 256
#define Z_PER_THREAD 16           // 512*256*16 = 2097152 >= 2000016

// K1: fused zero + dot, 8 tokens per wave (2048 waves, 512 blocks).
// Software-pipelined: issue loads for tokens 0-3, half the zero burst,
// loads for tokens 4-7, rest of the zero burst, then consume. 32 hidden
// float4 loads in flight per lane to maximize read-stream MLP.
__global__ __launch_bounds__(K1_THREADS) void k1_zero_and_dot(
    const float* __restrict__ hidden,   // [TOKENS, H]
    const float* __restrict__ mask,     // [TOKENS]
    const float* __restrict__ W,        // [H]
    const float* __restrict__ bias,     // [1]
    float* __restrict__ out,            // [B*V] — zeroed here
    float* __restrict__ tw_ws)          // [TOKENS]
{
    const int tid = blockIdx.x * K1_THREADS + threadIdx.x;
    const int lane = threadIdx.x & 63;
    const int wave = tid >> 6;          // 0..2047
    const int t0 = wave * 8;            // 8 tokens per wave

    // Broadcast operands first (scalar-load candidates, L1-resident).
    const float bias0 = bias[0];
    const float4 m4a = *reinterpret_cast<const float4*>(mask + t0);
    const float4 m4b = *reinterpret_cast<const float4*>(mask + t0 + 4);

    const float4* __restrict__ w4 = reinterpret_cast<const float4*>(W);
    float4 wv[4];
#pragma unroll
    for (int i = 0; i < 4; ++i) wv[i] = w4[i * 64 + lane];

    float4* __restrict__ o4 = reinterpret_cast<float4*>(out);
    const float4 z = make_float4(0.f, 0.f, 0.f, 0.f);
    const int zbase = blockIdx.x * (K1_THREADS * Z_PER_THREAD) + threadIdx.x;

    // ---- batch A loads (tokens 0-3): 16 float4 ----
    float4 h[8][4];
#pragma unroll
    for (int tt = 0; tt < 4; ++tt) {
        const float4* __restrict__ h4 =
            reinterpret_cast<const float4*>(hidden + (size_t)(t0 + tt) * HH);
#pragma unroll
        for (int i = 0; i < 4; ++i) h[tt][i] = h4[i * 64 + lane];
    }
    // ---- zero burst, first half ----
#pragma unroll
    for (int k = 0; k < Z_PER_THREAD / 2; ++k) {
        const int i = zbase + k * K1_THREADS;
        if (i < OUT_F4) o4[i] = z;
    }
    // ---- batch B loads (tokens 4-7): 16 float4 ----
#pragma unroll
    for (int tt = 4; tt < 8; ++tt) {
        const float4* __restrict__ h4 =
            reinterpret_cast<const float4*>(hidden + (size_t)(t0 + tt) * HH);
#pragma unroll
        for (int i = 0; i < 4; ++i) h[tt][i] = h4[i * 64 + lane];
    }
    // ---- zero burst, second half ----
#pragma unroll
    for (int k = Z_PER_THREAD / 2; k < Z_PER_THREAD; ++k) {
        const int i = zbase + k * K1_THREADS;
        if (i < OUT_F4) o4[i] = z;
    }

    // ---- consume ----
    float s[8];
#pragma unroll
    for (int tt = 0; tt < 8; ++tt) s[tt] = 0.f;
#pragma unroll
    for (int tt = 0; tt < 8; ++tt)
#pragma unroll
        for (int i = 0; i < 4; ++i) {
            s[tt] = fmaf(h[tt][i].x, wv[i].x, s[tt]);
            s[tt] = fmaf(h[tt][i].y, wv[i].y, s[tt]);
            s[tt] = fmaf(h[tt][i].z, wv[i].z, s[tt]);
            s[tt] = fmaf(h[tt][i].w, wv[i].w, s[tt]);
        }

#pragma unroll
    for (int off = 32; off > 0; off >>= 1) {
#pragma unroll
        for (int tt = 0; tt < 8; ++tt)
            s[tt] += __shfl_xor(s[tt], off, 64);
    }

    if (lane == 0) {
        float4 ra, rb;
        ra.x = fmaxf((s[0] + bias0) * m4a.x, 0.0f);
        ra.y = fmaxf((s[1] + bias0) * m4a.y, 0.0f);
        ra.z = fmaxf((s[2] + bias0) * m4a.z, 0.0f);
        ra.w = fmaxf((s[3] + bias0) * m4a.w, 0.0f);
        rb.x = fmaxf((s[4] + bias0) * m4b.x, 0.0f);
        rb.y = fmaxf((s[5] + bias0) * m4b.y, 0.0f);
        rb.z = fmaxf((s[6] + bias0) * m4b.z, 0.0f);
        rb.w = fmaxf((s[7] + bias0) * m4b.w, 0.0f);
        *reinterpret_cast<float4*>(tw_ws + t0)     = ra;
        *reinterpret_cast<float4*>(tw_ws + t0 + 4) = rb;
    }
}

// K2: scatter the 16384 token weights into out (runs after k1, stream order).
__global__ __launch_bounds__(256) void k2_scatter(
    const float* __restrict__ tw_ws,    // [TOKENS]
    const int* __restrict__ ids,        // [TOKENS]
    float* __restrict__ out)            // [B*V]
{
    const int t = blockIdx.x * 256 + threadIdx.x;
    if (t >= TOKENS) return;
    const float tw = tw_ws[t];
    if (tw != 0.0f)
        atomicAdd(&out[(size_t)(t / SS) * VV + ids[t]], tw);
}

extern "C" void kernel_launch(void* const* d_in, const int* in_sizes, int n_in,
                              void* d_out, int out_size, void* d_ws, size_t ws_size,
                              hipStream_t stream) {
    const float* hidden = (const float*)d_in[0];
    const int*   ids    = (const int*)d_in[1];
    const float* mask   = (const float*)d_in[2];
    const float* W      = (const float*)d_in[3];
    const float* bias   = (const float*)d_in[4];
    float* out   = (float*)d_out;
    float* tw_ws = (float*)d_ws;        // 16384 floats

    k1_zero_and_dot<<<K1_BLOCKS, K1_THREADS, 0, stream>>>(hidden, mask, W, bias, out, tw_ws);
    k2_scatter<<<(TOKENS + 255) / 256, 256, 0, stream>>>(tw_ws, ids, out);
}

// Round 11
// 21.361 us; speedup vs baseline: 1.0245x; 1.0245x over previous
//
#include <hip/hip_runtime.h>
#include <hip/hip_bf16.h>

// Problem constants (SparseEmbeddingHead): B=32, S=512, H=1024, V=250002
#define BB 32
#define SS 512
#define HH 1024
#define VV 250002
#define TOKENS (BB * SS)          // 16384
#define OUT_FLOATS (BB * VV)      // 8000064 (divisible by 4)
#define OUT_F4 (OUT_FLOATS / 4)   // 2000016

#define K1_BLOCKS 1024
#define K1_THREADS 256
#define Z_PER_THREAD 8            // 1024*256*8 = 2097152 >= 2000016

// Best-measured configuration (R9, 21.33 us): fused zero + dot, 4 tokens per
// wave (4096 waves, 1024 blocks), 16 hidden float4 loads in flight per lane,
// zero-store burst overlapped under the load latency, vectorized ws store.
// ILP sweep: 12 loads=21.76, 16 loads=21.33, 32 loads=21.88 -> 16 is optimal.
__global__ __launch_bounds__(K1_THREADS) void k1_zero_and_dot(
    const float* __restrict__ hidden,   // [TOKENS, H]
    const float* __restrict__ mask,     // [TOKENS]
    const float* __restrict__ W,        // [H]
    const float* __restrict__ bias,     // [1]
    float* __restrict__ out,            // [B*V] — zeroed here
    float* __restrict__ tw_ws)          // [TOKENS]
{
    const int tid = blockIdx.x * K1_THREADS + threadIdx.x;
    const int lane = threadIdx.x & 63;
    const int wave = tid >> 6;          // 0..4095
    const int t0 = wave * 4;            // 4 tokens per wave, 16B-aligned

    // Broadcast loads first (L1/L2-resident after first touch).
    const float bias0 = bias[0];
    const float4 m4 = *reinterpret_cast<const float4*>(mask + t0);

    const float4* __restrict__ w4 = reinterpret_cast<const float4*>(W);
    float4 wv[4];
#pragma unroll
    for (int i = 0; i < 4; ++i) wv[i] = w4[i * 64 + lane];

    // Issue 16 hidden loads (4 tokens x 4 float4/lane).
    float4 h[4][4];
#pragma unroll
    for (int tt = 0; tt < 4; ++tt) {
        const float4* __restrict__ h4 =
            reinterpret_cast<const float4*>(hidden + (size_t)(t0 + tt) * HH);
#pragma unroll
        for (int i = 0; i < 4; ++i) h[tt][i] = h4[i * 64 + lane];
    }

    // Zero-store burst while loads are in flight (block-contiguous slice).
    {
        float4* __restrict__ o4 = reinterpret_cast<float4*>(out);
        const float4 z = make_float4(0.f, 0.f, 0.f, 0.f);
        const int base = blockIdx.x * (K1_THREADS * Z_PER_THREAD) + threadIdx.x;
#pragma unroll
        for (int k = 0; k < Z_PER_THREAD; ++k) {
            const int i = base + k * K1_THREADS;
            if (i < OUT_F4) o4[i] = z;
        }
    }

    // Consume loads.
    float s[4] = {0.f, 0.f, 0.f, 0.f};
#pragma unroll
    for (int tt = 0; tt < 4; ++tt)
#pragma unroll
        for (int i = 0; i < 4; ++i) {
            s[tt] = fmaf(h[tt][i].x, wv[i].x, s[tt]);
            s[tt] = fmaf(h[tt][i].y, wv[i].y, s[tt]);
            s[tt] = fmaf(h[tt][i].z, wv[i].z, s[tt]);
            s[tt] = fmaf(h[tt][i].w, wv[i].w, s[tt]);
        }

#pragma unroll
    for (int off = 32; off > 0; off >>= 1) {
#pragma unroll
        for (int tt = 0; tt < 4; ++tt)
            s[tt] += __shfl_xor(s[tt], off, 64);
    }

    if (lane == 0) {
        float4 r;
        r.x = fmaxf((s[0] + bias0) * m4.x, 0.0f);
        r.y = fmaxf((s[1] + bias0) * m4.y, 0.0f);
        r.z = fmaxf((s[2] + bias0) * m4.z, 0.0f);
        r.w = fmaxf((s[3] + bias0) * m4.w, 0.0f);
        *reinterpret_cast<float4*>(tw_ws + t0) = r;
    }
}

// K2: scatter the 16384 token weights into out (runs after k1, stream order).
__global__ __launch_bounds__(256) void k2_scatter(
    const float* __restrict__ tw_ws,    // [TOKENS]
    const int* __restrict__ ids,        // [TOKENS]
    float* __restrict__ out)            // [B*V]
{
    const int t = blockIdx.x * 256 + threadIdx.x;
    if (t >= TOKENS) return;
    const float tw = tw_ws[t];
    if (tw != 0.0f)
        atomicAdd(&out[(size_t)(t / SS) * VV + ids[t]], tw);
}

extern "C" void kernel_launch(void* const* d_in, const int* in_sizes, int n_in,
                              void* d_out, int out_size, void* d_ws, size_t ws_size,
                              hipStream_t stream) {
    const float* hidden = (const float*)d_in[0];
    const int*   ids    = (const int*)d_in[1];
    const float* mask   = (const float*)d_in[2];
    const float* W      = (const float*)d_in[3];
    const float* bias   = (const float*)d_in[4];
    float* out   = (float*)d_out;
    float* tw_ws = (float*)d_ws;        // 16384 floats

    k1_zero_and_dot<<<K1_BLOCKS, K1_THREADS, 0, stream>>>(hidden, mask, W, bias, out, tw_ws);
    k2_scatter<<<(TOKENS + 255) / 256, 256, 0, stream>>>(tw_ws, ids, out);
}